// Round 10
// baseline (201.083 us; speedup 1.0000x reference)
//
#include <hip/hip_runtime.h>
#include <math.h>

// Problem: B=16384, D=512, R=64, E=8.
// out = x0 * (sum_e g_e * (x @ V[e]^T C[e] U[e]^T)) + g@b + x*sum(g)
// Folded: VCc[n=e*64+s][d] = sum_r V[e,r,d] C[e,r,s]  (Bt for GEMM1, K=d contig)
//         Ut [d][n=e*64+s] = U[e,d,s]                  (Bt for GEMM2, K=n contig)
//
// R12: R11 + occupancy bump on the GEMMs. Budget: ~89us fixed harness overhead,
// kernels ~70us (setup 10, gemm1 25, gemm2 35) vs ~45us floor. Both GEMMs were
// at 3 blk/CU; short-K (8 steps) + heavy epilogue leaves drain/burst gaps that
// a 4th co-resident block can cover. launch_bounds(256,4) (VGPR cap 128, fits
// ~112 used). gemm2's bb[4][8] hoist (32 VGPR) replaced by an LDS-staged bvec
// tile (4KB, async16, drained by core's first barrier) so the cap is safe.
// LDS 40960B x 4 = exactly 160KB/CU. Core & numerics bit-identical to R11.
// Top-5 dispatches are harness 256MiB fills (~41us @82% HBM) — fixed overhead.

typedef __bf16 bf16_t;
typedef __attribute__((ext_vector_type(8))) __bf16 bf16x8;
typedef __attribute__((ext_vector_type(4))) __bf16 bf16x4;
typedef __attribute__((ext_vector_type(4))) float  floatx4;

#define MFMA16 __builtin_amdgcn_mfma_f32_16x16x32_bf16

// async 16B/lane global->LDS (LDS dest = wave-uniform base + lane*16)
__device__ __forceinline__ void async16(void* lds, const void* gp) {
  __builtin_amdgcn_global_load_lds(
      (__attribute__((address_space(1))) void*)(gp),
      (__attribute__((address_space(3))) void*)(lds), 16, 0, 0);
}

// ---------------- K0: setup = weight prep (blocks 0..127) + gate (128..4223) --
__global__ __launch_bounds__(256) void setup_kernel(
    const float* __restrict__ U, const float* __restrict__ V, const float* __restrict__ C,
    const float* __restrict__ x, const float* __restrict__ Wg, const float* __restrict__ bg,
    bf16_t* __restrict__ VCc, bf16_t* __restrict__ Ut,
    bf16_t* __restrict__ xbf, float* __restrict__ g) {
  __shared__ alignas(16) char ldsbuf[32768];
  const int t = threadIdx.x;
  if (blockIdx.x < 128) {
    const int b = blockIdx.x;
    if (b < 64) {
      float* ldsC = (float*)ldsbuf;            // [64 r][64 s]
      float* ldsV = (float*)(ldsbuf + 16384);  // [64 r][64 d]
      const int e = b >> 3, db = b & 7;
#pragma unroll
      for (int i = 0; i < 4; ++i) {
        int c = i * 256 + t;
        async16(ldsbuf + c * 16, (const char*)C + (size_t)e * 16384 + c * 16);
      }
#pragma unroll
      for (int i = 0; i < 4; ++i) {
        int c = i * 256 + t, r = c >> 4, cc = c & 15;
        async16(ldsbuf + 16384 + c * 16,
                (const char*)V + (size_t)(e * 64 + r) * 2048 + db * 256 + cc * 16);
      }
      __syncthreads();
      const int s = t & 63, dg = t >> 6;
      float acc16[16];
#pragma unroll
      for (int k = 0; k < 16; ++k) acc16[k] = 0.f;
#pragma unroll 4
      for (int r = 0; r < 64; ++r) {
        float cv = ldsC[r * 64 + s];
        floatx4 v[4];
#pragma unroll
        for (int j = 0; j < 4; ++j) v[j] = *(const floatx4*)(ldsV + r * 64 + dg * 16 + j * 4);
#pragma unroll
        for (int j = 0; j < 4; ++j)
#pragma unroll
          for (int k = 0; k < 4; ++k) acc16[j * 4 + k] = fmaf(v[j][k], cv, acc16[j * 4 + k]);
      }
      bf16_t* dst = VCc + (size_t)(e * 64 + s) * 512 + db * 64 + dg * 16;
      bf16x8 o0, o1;
#pragma unroll
      for (int k = 0; k < 8; ++k) { o0[k] = (bf16_t)acc16[k]; o1[k] = (bf16_t)acc16[8 + k]; }
      *(bf16x8*)dst = o0;
      *(bf16x8*)(dst + 8) = o1;
    } else {
      const int base = (b - 64) * 4096 + t * 16;
      const int d = base >> 9, n0 = base & 511;
      const int e = n0 >> 6, s0 = n0 & 63;
      const float* src = U + ((size_t)e * 512 + d) * 64 + s0;
      bf16x8 o0, o1;
#pragma unroll
      for (int k = 0; k < 8; ++k) { o0[k] = (bf16_t)src[k]; o1[k] = (bf16_t)src[8 + k]; }
      *(bf16x8*)(Ut + base) = o0;
      *(bf16x8*)(Ut + base + 8) = o1;
    }
  } else {
    // ---- gate path (verbatim-verified): row = (blk-128)*4 + wave ----
    int wave = t >> 6, lane = t & 63;
    int row = (blockIdx.x - 128) * 4 + wave;
    const float4* xr = (const float4*)(x + (size_t)row * 512);
    float4 v0 = xr[lane];
    float4 v1 = xr[lane + 64];
    bf16x4* xb = (bf16x4*)(xbf + (size_t)row * 512);
    bf16x4 b0, b1;
    b0.x = (bf16_t)v0.x; b0.y = (bf16_t)v0.y; b0.z = (bf16_t)v0.z; b0.w = (bf16_t)v0.w;
    b1.x = (bf16_t)v1.x; b1.y = (bf16_t)v1.y; b1.z = (bf16_t)v1.z; b1.w = (bf16_t)v1.w;
    xb[lane] = b0;
    xb[lane + 64] = b1;
    float acc[8];
#pragma unroll
    for (int e = 0; e < 8; ++e) {
      const float4* wp = (const float4*)(Wg + (size_t)e * 512);
      float4 w0 = wp[lane], w1 = wp[lane + 64];
      acc[e] = v0.x * w0.x + v0.y * w0.y + v0.z * w0.z + v0.w * w0.w +
               v1.x * w1.x + v1.y * w1.y + v1.z * w1.z + v1.w * w1.w;
    }
#pragma unroll
    for (int e = 0; e < 8; ++e) {
#pragma unroll
      for (int off = 32; off > 0; off >>= 1) acc[e] += __shfl_xor(acc[e], off, 64);
    }
    float z[8], mx = -1e30f;
#pragma unroll
    for (int e = 0; e < 8; ++e) { z[e] = acc[e] + bg[e]; mx = fmaxf(mx, z[e]); }
    float s = 0.f;
#pragma unroll
    for (int e = 0; e < 8; ++e) { z[e] = __expf(z[e] - mx); s += z[e]; }
    float inv = 1.f / s;
    if (lane == 0) {
#pragma unroll
      for (int e = 0; e < 8; ++e) g[(size_t)row * 8 + e] = z[e] * inv;
    }
  }
}

// ---------------- shared GEMM core: 128x128 tile, BK=64, 4 waves 64x64 -----
// A [M][512] bf16 row-major; Bt [N][512] bf16 (column n's K contiguous).
// LDS chunk swizzle: 16B slot q of row r holds global slot q^(r&7) within the
// 128B row (inverse-swizzled source, linear global_load_lds dest; read XORs
// back). Single-buffered, 2 barriers/K-step; co-resident blocks absorb drains.
__device__ __forceinline__ void gemm_core128(
    char* lds, const bf16_t* __restrict__ A, const bf16_t* __restrict__ Bt,
    int m0, int n0, int t, floatx4 acc[4][4]) {
  char* ldsA = lds;           // [128 rows][128B]
  char* ldsB = lds + 16384;   // [128 rows][128B]
  const int wave = t >> 6, lane = t & 63;
  const int wr = wave >> 1, wc = wave & 1;
  const int lhi = lane >> 4, llo = lane & 15;
#pragma unroll 1
  for (int kt = 0; kt < 8; ++kt) {
    __syncthreads();  // protect LDS from previous iter's readers
#pragma unroll
    for (int i = 0; i < 4; ++i) {          // A: 1024 slots of 16B
      int c = i * 256 + t, r = c >> 3, q = c & 7, p = q ^ (r & 7);
      async16(ldsA + (i * 256 + wave * 64) * 16,
              (const char*)A + (size_t)(m0 + r) * 1024 + kt * 128 + p * 16);
    }
#pragma unroll
    for (int i = 0; i < 4; ++i) {          // B: 1024 slots of 16B
      int c = i * 256 + t, r = c >> 3, q = c & 7, p = q ^ (r & 7);
      async16(ldsB + (i * 256 + wave * 64) * 16,
              (const char*)Bt + (size_t)(n0 + r) * 1024 + kt * 128 + p * 16);
    }
    __syncthreads();  // drains vmcnt per barrier semantics
#pragma unroll
    for (int ks = 0; ks < 2; ++ks) {
      bf16x8 af[4], bfm[4];
#pragma unroll
      for (int i = 0; i < 4; ++i) {
        int r = wr * 64 + i * 16 + llo;    // A-frag: row=lane&15(+tile), k=quad*8+j
        af[i] = *(const bf16x8*)(ldsA + r * 128 + (((ks * 4 + lhi) ^ (r & 7)) << 4));
      }
#pragma unroll
      for (int j = 0; j < 4; ++j) {
        int r = wc * 64 + j * 16 + llo;    // B-frag: col=lane&15(+tile)
        bfm[j] = *(const bf16x8*)(ldsB + r * 128 + (((ks * 4 + lhi) ^ (r & 7)) << 4));
      }
#pragma unroll
      for (int i = 0; i < 4; ++i)
#pragma unroll
        for (int j = 0; j < 4; ++j)
          acc[i][j] = MFMA16(af[i], bfm[j], acc[i][j], 0, 0, 0);
    }
  }
}

// ---------------- K2: GEMM1 + gate-scale epilogue -> T (bf16) --------------
__global__ __launch_bounds__(256, 4) void gemm1_kernel(
    const bf16_t* __restrict__ xbf, const bf16_t* __restrict__ VCc,
    const float* __restrict__ g, bf16_t* __restrict__ T) {
  __shared__ alignas(16) char lds[36864];
  float* ldsGf = (float*)(lds + 32768);    // [128 rows][8] gates
  int t = threadIdx.x;
  int m0 = blockIdx.x * 128, n0 = blockIdx.y * 128;
  // stage g-tile (4KB) — drained by core's first __syncthreads
  async16(ldsGf + (t >> 6) * 256, (const char*)g + (size_t)m0 * 32 + t * 16);
  floatx4 acc[4][4];
#pragma unroll
  for (int i = 0; i < 4; ++i)
#pragma unroll
    for (int j = 0; j < 4; ++j) acc[i][j] = (floatx4){0.f, 0.f, 0.f, 0.f};
  gemm_core128(lds, xbf, VCc, m0, n0, t, acc);
  const int wave = t >> 6, lane = t & 63;
  const int wr = wave >> 1, wc = wave & 1;
  const int lhi = lane >> 4, llo = lane & 15;
  const int e = (n0 >> 6) + wc;  // 64-col block = one expert (wave-uniform)
  // ---- epilogue: gate-scale -> LDS bf16 [128 rows][256B] (swz) -> coalesced T
  // acc consumed immediately after one barrier: no cross-barrier liveness.
  __syncthreads();               // all waves done reading ldsA/ldsB
#pragma unroll
  for (int i = 0; i < 4; ++i) {
#pragma unroll
    for (int r = 0; r < 4; ++r) {
      int lrow = wr * 64 + i * 16 + lhi * 4 + r;    // C/D: col=lane&15, row=quad*4+reg
      float gv = ldsGf[lrow * 8 + e];
#pragma unroll
      for (int j = 0; j < 4; ++j) {
        int c = wc * 64 + j * 16 + llo;             // block-local col
        int q = c >> 3;
        *(bf16_t*)(lds + lrow * 256 + ((q ^ (lrow & 7)) << 4) + (c & 7) * 2) =
            (bf16_t)(acc[i][j][r] * gv);
      }
    }
  }
  __syncthreads();
  {
    const int s = t & 15, r0 = t >> 4, rm = r0 & 7;
#pragma unroll
    for (int i = 0; i < 8; ++i) {
      int r = r0 + i * 16;                          // (r&7)==rm
      bf16x8 v = *(const bf16x8*)(lds + r * 256 + ((s ^ rm) << 4));
      *(bf16x8*)((char*)T + (size_t)(m0 + r) * 1024 + n0 * 2 + s * 16) = v;
    }
  }
}

// ---------------- K3: GEMM2 + final epilogue -> out (f32) ------------------
// R9-form inline-consume epilogue; bvec tile moved to LDS (saves 32 VGPR so
// the 4-blk/CU register cap is safe). Each store instr covers 4x64B lines.
__global__ __launch_bounds__(256, 4) void gemm2_kernel(
    const bf16_t* __restrict__ T, const bf16_t* __restrict__ Ut,
    const float* __restrict__ g, const float* __restrict__ bvec,
    const float* __restrict__ x0, const float* __restrict__ x,
    float* __restrict__ out) {
  __shared__ alignas(16) char lds[40960];
  float* ldsGf = (float*)(lds + 32768);    // [128 rows][8] gates
  float* ldsBv = (float*)(lds + 36864);    // [8 experts][128 cols] bvec tile
  int t = threadIdx.x;
  int m0 = blockIdx.x * 128, n0 = blockIdx.y * 128;
  async16(ldsGf + (t >> 6) * 256, (const char*)g + (size_t)m0 * 32 + t * 16);
  // stage bvec tile (4KB): thread t -> expert t>>5, cols (t&31)*4..+4
  async16(ldsBv + (t >> 6) * 1024,
          (const char*)bvec + (size_t)(t >> 5) * 2048 + n0 * 4 + (t & 31) * 16);
  floatx4 acc[4][4];
#pragma unroll
  for (int i = 0; i < 4; ++i)
#pragma unroll
    for (int j = 0; j < 4; ++j) acc[i][j] = (floatx4){0.f, 0.f, 0.f, 0.f};
  gemm_core128(lds, T, Ut, m0, n0, t, acc);
  const int wave = t >> 6, lane = t & 63;
  const int wr = wave >> 1, wc = wave & 1;
  const int lhi = lane >> 4, llo = lane & 15;
#pragma unroll
  for (int i = 0; i < 4; ++i) {
#pragma unroll
    for (int r = 0; r < 4; ++r) {
      int lrow = wr * 64 + i * 16 + lhi * 4 + r;
      floatx4 ga = *(const floatx4*)(ldsGf + lrow * 8);
      floatx4 gb = *(const floatx4*)(ldsGf + lrow * 8 + 4);
      float g8[8] = {ga[0], ga[1], ga[2], ga[3], gb[0], gb[1], gb[2], gb[3]};
      float gsum = ga[0] + ga[1] + ga[2] + ga[3] + gb[0] + gb[1] + gb[2] + gb[3];
#pragma unroll
      for (int j = 0; j < 4; ++j) {
        int c = wc * 64 + j * 16 + llo;             // block-local col
        float bias = 0.f;
#pragma unroll
        for (int e = 0; e < 8; ++e) bias += g8[e] * ldsBv[e * 128 + c];
        size_t idx = (size_t)(m0 + lrow) * 512 + n0 + c;
        out[idx] = x0[idx] * acc[i][j][r] + bias + x[idx] * gsum;
      }
    }
  }
}

// ---------------- launch ----------------------------------------------------
extern "C" void kernel_launch(void* const* d_in, const int* in_sizes, int n_in,
                              void* d_out, int out_size, void* d_ws, size_t ws_size,
                              hipStream_t stream) {
  const float* x0 = (const float*)d_in[0];
  const float* x  = (const float*)d_in[1];
  const float* U  = (const float*)d_in[2];
  const float* V  = (const float*)d_in[3];
  const float* C  = (const float*)d_in[4];
  const float* bv = (const float*)d_in[5];
  const float* Wg = (const float*)d_in[6];
  const float* bg = (const float*)d_in[7];
  float* out = (float*)d_out;

  char* ws = (char*)d_ws;
  bf16_t* xbf = (bf16_t*)(ws);                               // 16,777,216 B
  bf16_t* T   = (bf16_t*)(ws + 16777216);                    // 16,777,216 B
  bf16_t* VCc = (bf16_t*)(ws + 33554432);                    //    524,288 B
  bf16_t* Ut  = (bf16_t*)(ws + 34078720);                    //    524,288 B
  float*  g   = (float*)(ws + 34603008);                     //    524,288 B

  setup_kernel<<<4224, 256, 0, stream>>>(U, V, C, x, Wg, bg, VCc, Ut, xbf, g);
  gemm1_kernel<<<dim3(128, 4), 256, 0, stream>>>(xbf, VCc, g, T);
  gemm2_kernel<<<dim3(128, 4), 256, 0, stream>>>(T, Ut, g, bv, x0, x, out);
}

// Round 11
// 157.776 us; speedup vs baseline: 1.2745x; 1.2745x over previous
//
#include <hip/hip_runtime.h>
#include <math.h>

// Problem: B=16384, D=512, R=64, E=8.
// out = x0 * (sum_e g_e * (x @ V[e]^T C[e] U[e]^T)) + g@b + x*sum(g)
// Folded: VCc[n=e*64+s][d] = sum_r V[e,r,d] C[e,r,s]  (Bt for GEMM1, K=d contig)
//         Ut [d][n=e*64+s] = U[e,d,s]                  (Bt for GEMM2, K=n contig)
//
// R13 = exact revert to R11 (best verified: 158.6us, absmax 0.03125).
// R12's launch_bounds(256,4) made the allocator pick 64 VGPR -> acc spill
// (WRITE 42MB vs 33MB, gemm2 79us) and its bvec LDS staging was out-of-bounds
// (absmax doubled; masked only because b==0 in this test). Both reverted.
// R11 = verified 128x128 drain-core GEMMs at 3 blk/CU + merged setup +
// g-tile LDS staging + gemm1 coalesced T-store + gemm2 inline-consume epilogue.
// Ledger: ~89us fixed harness fills/resets + ~70us kernels (floor ~45us);
// remaining gap is allocator-fragile — further perturbation has negative EV.

typedef __bf16 bf16_t;
typedef __attribute__((ext_vector_type(8))) __bf16 bf16x8;
typedef __attribute__((ext_vector_type(4))) __bf16 bf16x4;
typedef __attribute__((ext_vector_type(4))) float  floatx4;

#define MFMA16 __builtin_amdgcn_mfma_f32_16x16x32_bf16

// async 16B/lane global->LDS (LDS dest = wave-uniform base + lane*16)
__device__ __forceinline__ void async16(void* lds, const void* gp) {
  __builtin_amdgcn_global_load_lds(
      (__attribute__((address_space(1))) void*)(gp),
      (__attribute__((address_space(3))) void*)(lds), 16, 0, 0);
}

// ---------------- K0: setup = weight prep (blocks 0..127) + gate (128..4223) --
__global__ __launch_bounds__(256) void setup_kernel(
    const float* __restrict__ U, const float* __restrict__ V, const float* __restrict__ C,
    const float* __restrict__ x, const float* __restrict__ Wg, const float* __restrict__ bg,
    bf16_t* __restrict__ VCc, bf16_t* __restrict__ Ut,
    bf16_t* __restrict__ xbf, float* __restrict__ g) {
  __shared__ alignas(16) char ldsbuf[32768];
  const int t = threadIdx.x;
  if (blockIdx.x < 128) {
    const int b = blockIdx.x;
    if (b < 64) {
      float* ldsC = (float*)ldsbuf;            // [64 r][64 s]
      float* ldsV = (float*)(ldsbuf + 16384);  // [64 r][64 d]
      const int e = b >> 3, db = b & 7;
#pragma unroll
      for (int i = 0; i < 4; ++i) {
        int c = i * 256 + t;
        async16(ldsbuf + c * 16, (const char*)C + (size_t)e * 16384 + c * 16);
      }
#pragma unroll
      for (int i = 0; i < 4; ++i) {
        int c = i * 256 + t, r = c >> 4, cc = c & 15;
        async16(ldsbuf + 16384 + c * 16,
                (const char*)V + (size_t)(e * 64 + r) * 2048 + db * 256 + cc * 16);
      }
      __syncthreads();
      const int s = t & 63, dg = t >> 6;
      float acc16[16];
#pragma unroll
      for (int k = 0; k < 16; ++k) acc16[k] = 0.f;
#pragma unroll 4
      for (int r = 0; r < 64; ++r) {
        float cv = ldsC[r * 64 + s];
        floatx4 v[4];
#pragma unroll
        for (int j = 0; j < 4; ++j) v[j] = *(const floatx4*)(ldsV + r * 64 + dg * 16 + j * 4);
#pragma unroll
        for (int j = 0; j < 4; ++j)
#pragma unroll
          for (int k = 0; k < 4; ++k) acc16[j * 4 + k] = fmaf(v[j][k], cv, acc16[j * 4 + k]);
      }
      bf16_t* dst = VCc + (size_t)(e * 64 + s) * 512 + db * 64 + dg * 16;
      bf16x8 o0, o1;
#pragma unroll
      for (int k = 0; k < 8; ++k) { o0[k] = (bf16_t)acc16[k]; o1[k] = (bf16_t)acc16[8 + k]; }
      *(bf16x8*)dst = o0;
      *(bf16x8*)(dst + 8) = o1;
    } else {
      const int base = (b - 64) * 4096 + t * 16;
      const int d = base >> 9, n0 = base & 511;
      const int e = n0 >> 6, s0 = n0 & 63;
      const float* src = U + ((size_t)e * 512 + d) * 64 + s0;
      bf16x8 o0, o1;
#pragma unroll
      for (int k = 0; k < 8; ++k) { o0[k] = (bf16_t)src[k]; o1[k] = (bf16_t)src[8 + k]; }
      *(bf16x8*)(Ut + base) = o0;
      *(bf16x8*)(Ut + base + 8) = o1;
    }
  } else {
    // ---- gate path (verbatim-verified): row = (blk-128)*4 + wave ----
    int wave = t >> 6, lane = t & 63;
    int row = (blockIdx.x - 128) * 4 + wave;
    const float4* xr = (const float4*)(x + (size_t)row * 512);
    float4 v0 = xr[lane];
    float4 v1 = xr[lane + 64];
    bf16x4* xb = (bf16x4*)(xbf + (size_t)row * 512);
    bf16x4 b0, b1;
    b0.x = (bf16_t)v0.x; b0.y = (bf16_t)v0.y; b0.z = (bf16_t)v0.z; b0.w = (bf16_t)v0.w;
    b1.x = (bf16_t)v1.x; b1.y = (bf16_t)v1.y; b1.z = (bf16_t)v1.z; b1.w = (bf16_t)v1.w;
    xb[lane] = b0;
    xb[lane + 64] = b1;
    float acc[8];
#pragma unroll
    for (int e = 0; e < 8; ++e) {
      const float4* wp = (const float4*)(Wg + (size_t)e * 512);
      float4 w0 = wp[lane], w1 = wp[lane + 64];
      acc[e] = v0.x * w0.x + v0.y * w0.y + v0.z * w0.z + v0.w * w0.w +
               v1.x * w1.x + v1.y * w1.y + v1.z * w1.z + v1.w * w1.w;
    }
#pragma unroll
    for (int e = 0; e < 8; ++e) {
#pragma unroll
      for (int off = 32; off > 0; off >>= 1) acc[e] += __shfl_xor(acc[e], off, 64);
    }
    float z[8], mx = -1e30f;
#pragma unroll
    for (int e = 0; e < 8; ++e) { z[e] = acc[e] + bg[e]; mx = fmaxf(mx, z[e]); }
    float s = 0.f;
#pragma unroll
    for (int e = 0; e < 8; ++e) { z[e] = __expf(z[e] - mx); s += z[e]; }
    float inv = 1.f / s;
    if (lane == 0) {
#pragma unroll
      for (int e = 0; e < 8; ++e) g[(size_t)row * 8 + e] = z[e] * inv;
    }
  }
}

// ---------------- shared GEMM core: 128x128 tile, BK=64, 4 waves 64x64 -----
// A [M][512] bf16 row-major; Bt [N][512] bf16 (column n's K contiguous).
// LDS chunk swizzle: 16B slot q of row r holds global slot q^(r&7) within the
// 128B row (inverse-swizzled source, linear global_load_lds dest; read XORs
// back). Single-buffered, 2 barriers/K-step; co-resident blocks absorb drains.
__device__ __forceinline__ void gemm_core128(
    char* lds, const bf16_t* __restrict__ A, const bf16_t* __restrict__ Bt,
    int m0, int n0, int t, floatx4 acc[4][4]) {
  char* ldsA = lds;           // [128 rows][128B]
  char* ldsB = lds + 16384;   // [128 rows][128B]
  const int wave = t >> 6, lane = t & 63;
  const int wr = wave >> 1, wc = wave & 1;
  const int lhi = lane >> 4, llo = lane & 15;
#pragma unroll 1
  for (int kt = 0; kt < 8; ++kt) {
    __syncthreads();  // protect LDS from previous iter's readers
#pragma unroll
    for (int i = 0; i < 4; ++i) {          // A: 1024 slots of 16B
      int c = i * 256 + t, r = c >> 3, q = c & 7, p = q ^ (r & 7);
      async16(ldsA + (i * 256 + wave * 64) * 16,
              (const char*)A + (size_t)(m0 + r) * 1024 + kt * 128 + p * 16);
    }
#pragma unroll
    for (int i = 0; i < 4; ++i) {          // B: 1024 slots of 16B
      int c = i * 256 + t, r = c >> 3, q = c & 7, p = q ^ (r & 7);
      async16(ldsB + (i * 256 + wave * 64) * 16,
              (const char*)Bt + (size_t)(n0 + r) * 1024 + kt * 128 + p * 16);
    }
    __syncthreads();  // drains vmcnt per barrier semantics
#pragma unroll
    for (int ks = 0; ks < 2; ++ks) {
      bf16x8 af[4], bfm[4];
#pragma unroll
      for (int i = 0; i < 4; ++i) {
        int r = wr * 64 + i * 16 + llo;    // A-frag: row=lane&15(+tile), k=quad*8+j
        af[i] = *(const bf16x8*)(ldsA + r * 128 + (((ks * 4 + lhi) ^ (r & 7)) << 4));
      }
#pragma unroll
      for (int j = 0; j < 4; ++j) {
        int r = wc * 64 + j * 16 + llo;    // B-frag: col=lane&15(+tile)
        bfm[j] = *(const bf16x8*)(ldsB + r * 128 + (((ks * 4 + lhi) ^ (r & 7)) << 4));
      }
#pragma unroll
      for (int i = 0; i < 4; ++i)
#pragma unroll
        for (int j = 0; j < 4; ++j)
          acc[i][j] = MFMA16(af[i], bfm[j], acc[i][j], 0, 0, 0);
    }
  }
}

// ---------------- K2: GEMM1 + gate-scale epilogue -> T (bf16) --------------
__global__ __launch_bounds__(256, 3) void gemm1_kernel(
    const bf16_t* __restrict__ xbf, const bf16_t* __restrict__ VCc,
    const float* __restrict__ g, bf16_t* __restrict__ T) {
  __shared__ alignas(16) char lds[36864];
  float* ldsGf = (float*)(lds + 32768);    // [128 rows][8] gates
  int t = threadIdx.x;
  int m0 = blockIdx.x * 128, n0 = blockIdx.y * 128;
  // stage g-tile (4KB) — drained by core's first __syncthreads
  async16(ldsGf + (t >> 6) * 256, (const char*)g + (size_t)m0 * 32 + t * 16);
  floatx4 acc[4][4];
#pragma unroll
  for (int i = 0; i < 4; ++i)
#pragma unroll
    for (int j = 0; j < 4; ++j) acc[i][j] = (floatx4){0.f, 0.f, 0.f, 0.f};
  gemm_core128(lds, xbf, VCc, m0, n0, t, acc);
  const int wave = t >> 6, lane = t & 63;
  const int wr = wave >> 1, wc = wave & 1;
  const int lhi = lane >> 4, llo = lane & 15;
  const int e = (n0 >> 6) + wc;  // 64-col block = one expert (wave-uniform)
  // ---- epilogue: gate-scale -> LDS bf16 [128 rows][256B] (swz) -> coalesced T
  // acc consumed immediately after one barrier: no cross-barrier liveness.
  __syncthreads();               // all waves done reading ldsA/ldsB
#pragma unroll
  for (int i = 0; i < 4; ++i) {
#pragma unroll
    for (int r = 0; r < 4; ++r) {
      int lrow = wr * 64 + i * 16 + lhi * 4 + r;    // C/D: col=lane&15, row=quad*4+reg
      float gv = ldsGf[lrow * 8 + e];
#pragma unroll
      for (int j = 0; j < 4; ++j) {
        int c = wc * 64 + j * 16 + llo;             // block-local col
        int q = c >> 3;
        *(bf16_t*)(lds + lrow * 256 + ((q ^ (lrow & 7)) << 4) + (c & 7) * 2) =
            (bf16_t)(acc[i][j][r] * gv);
      }
    }
  }
  __syncthreads();
  {
    const int s = t & 15, r0 = t >> 4, rm = r0 & 7;
#pragma unroll
    for (int i = 0; i < 8; ++i) {
      int r = r0 + i * 16;                          // (r&7)==rm
      bf16x8 v = *(const bf16x8*)(lds + r * 256 + ((s ^ rm) << 4));
      *(bf16x8*)((char*)T + (size_t)(m0 + r) * 1024 + n0 * 2 + s * 16) = v;
    }
  }
}

// ---------------- K3: GEMM2 + final epilogue -> out (f32) ------------------
// R9-form epilogue: acc consumed inline (no spill); each scalar-store instr
// covers 4x64B full cache lines (llo spans 16 contiguous f32).
__global__ __launch_bounds__(256, 3) void gemm2_kernel(
    const bf16_t* __restrict__ T, const bf16_t* __restrict__ Ut,
    const float* __restrict__ g, const float* __restrict__ bvec,
    const float* __restrict__ x0, const float* __restrict__ x,
    float* __restrict__ out) {
  __shared__ alignas(16) char lds[36864];
  float* ldsGf = (float*)(lds + 32768);    // [128 rows][8] gates
  int t = threadIdx.x;
  int m0 = blockIdx.x * 128, n0 = blockIdx.y * 128;
  async16(ldsGf + (t >> 6) * 256, (const char*)g + (size_t)m0 * 32 + t * 16);
  floatx4 acc[4][4];
#pragma unroll
  for (int i = 0; i < 4; ++i)
#pragma unroll
    for (int j = 0; j < 4; ++j) acc[i][j] = (floatx4){0.f, 0.f, 0.f, 0.f};
  gemm_core128(lds, T, Ut, m0, n0, t, acc);
  const int wave = t >> 6, lane = t & 63;
  const int wr = wave >> 1, wc = wave & 1;
  const int lhi = lane >> 4, llo = lane & 15;
  float bb[4][8];  // bvec[e][n_j] for this lane's 4 column positions
#pragma unroll
  for (int j = 0; j < 4; ++j) {
    int n = n0 + wc * 64 + j * 16 + llo;
#pragma unroll
    for (int e = 0; e < 8; ++e) bb[j][e] = bvec[(size_t)e * 512 + n];
  }
#pragma unroll
  for (int i = 0; i < 4; ++i) {
#pragma unroll
    for (int r = 0; r < 4; ++r) {
      int lrow = wr * 64 + i * 16 + lhi * 4 + r;
      floatx4 ga = *(const floatx4*)(ldsGf + lrow * 8);
      floatx4 gb = *(const floatx4*)(ldsGf + lrow * 8 + 4);
      float g8[8] = {ga[0], ga[1], ga[2], ga[3], gb[0], gb[1], gb[2], gb[3]};
      float gsum = ga[0] + ga[1] + ga[2] + ga[3] + gb[0] + gb[1] + gb[2] + gb[3];
#pragma unroll
      for (int j = 0; j < 4; ++j) {
        int n = n0 + wc * 64 + j * 16 + llo;
        float bias = 0.f;
#pragma unroll
        for (int e = 0; e < 8; ++e) bias += g8[e] * bb[j][e];
        size_t idx = (size_t)(m0 + lrow) * 512 + n;
        out[idx] = x0[idx] * acc[i][j][r] + bias + x[idx] * gsum;
      }
    }
  }
}

// ---------------- launch ----------------------------------------------------
extern "C" void kernel_launch(void* const* d_in, const int* in_sizes, int n_in,
                              void* d_out, int out_size, void* d_ws, size_t ws_size,
                              hipStream_t stream) {
  const float* x0 = (const float*)d_in[0];
  const float* x  = (const float*)d_in[1];
  const float* U  = (const float*)d_in[2];
  const float* V  = (const float*)d_in[3];
  const float* C  = (const float*)d_in[4];
  const float* bv = (const float*)d_in[5];
  const float* Wg = (const float*)d_in[6];
  const float* bg = (const float*)d_in[7];
  float* out = (float*)d_out;

  char* ws = (char*)d_ws;
  bf16_t* xbf = (bf16_t*)(ws);                               // 16,777,216 B
  bf16_t* T   = (bf16_t*)(ws + 16777216);                    // 16,777,216 B
  bf16_t* VCc = (bf16_t*)(ws + 33554432);                    //    524,288 B
  bf16_t* Ut  = (bf16_t*)(ws + 34078720);                    //    524,288 B
  float*  g   = (float*)(ws + 34603008);                     //    524,288 B

  setup_kernel<<<4224, 256, 0, stream>>>(U, V, C, x, Wg, bg, VCc, Ut, xbf, g);
  gemm1_kernel<<<dim3(128, 4), 256, 0, stream>>>(xbf, VCc, g, T);
  gemm2_kernel<<<dim3(128, 4), 256, 0, stream>>>(T, Ut, g, bv, x0, x, out);
}